// Round 1
// baseline (873.718 us; speedup 1.0000x reference)
//
#include <hip/hip_runtime.h>
#include <math.h>

#define B_ 8
#define L_ 2048
#define D_ 256
#define NEG_INF_V (-1e10f)
#define SPLIT 2
#define PT 64
#define ST 64
#define DK 32

// ---------- K1: per-row sum of squares (one wave per row) ----------
__global__ __launch_bounds__(256) void rowsq_kernel(const float* __restrict__ x,
                                                    float* __restrict__ out) {
    int row = blockIdx.x * 4 + (threadIdx.x >> 6);
    int lane = threadIdx.x & 63;
    const float4* p = (const float4*)(x + (size_t)row * D_);
    float4 v = p[lane];
    float s = v.x * v.x + v.y * v.y + v.z * v.z + v.w * v.w;
    #pragma unroll
    for (int o = 32; o > 0; o >>= 1) s += __shfl_xor(s, o, 64);
    if (lane == 0) out[row] = s;
}

// ---------- K2: predW[m,n] = sum_k pred[m,k] * W[k,n]  (M=B*L, K=N=256) ----------
__global__ __launch_bounds__(256) void predw_kernel(const float* __restrict__ pred,
                                                    const float* __restrict__ W,
                                                    float* __restrict__ out) {
    __shared__ float sA[16][68];  // [k][m], padded
    __shared__ float sB[16][68];  // [k][n], padded
    int tid = threadIdx.x;
    int tx = tid & 15, ty = tid >> 4;
    int m0 = blockIdx.x * 64;
    int n0 = blockIdx.y * 64;
    float acc[4][4] = {};
    #pragma unroll 1
    for (int k0 = 0; k0 < D_; k0 += 16) {
        {
            int r = tid >> 2, c4 = (tid & 3) * 4;
            float4 v = *(const float4*)(pred + (size_t)(m0 + r) * D_ + k0 + c4);
            sA[c4 + 0][r] = v.x; sA[c4 + 1][r] = v.y;
            sA[c4 + 2][r] = v.z; sA[c4 + 3][r] = v.w;
            int r2 = tid >> 4, c42 = (tid & 15) * 4;
            *(float4*)&sB[r2][c42] = *(const float4*)(W + (size_t)(k0 + r2) * D_ + n0 + c42);
        }
        __syncthreads();
        #pragma unroll
        for (int k = 0; k < 16; k++) {
            float4 a = *(const float4*)&sA[k][ty * 4];
            float4 b = *(const float4*)&sB[k][tx * 4];
            const float* av = (const float*)&a;
            const float* bv = (const float*)&b;
            #pragma unroll
            for (int i = 0; i < 4; i++)
                #pragma unroll
                for (int j = 0; j < 4; j++) acc[i][j] = fmaf(av[i], bv[j], acc[i][j]);
        }
        __syncthreads();
    }
    #pragma unroll
    for (int i = 0; i < 4; i++) {
        float4 v = {acc[i][0], acc[i][1], acc[i][2], acc[i][3]};
        *(float4*)(out + (size_t)(m0 + ty * 4 + i) * D_ + n0 + tx * 4) = v;
    }
}

__device__ __forceinline__ float rowmax16(float v) {
    #pragma unroll
    for (int o = 8; o > 0; o >>= 1) v = fmaxf(v, __shfl_xor(v, o, 16));
    return v;
}
__device__ __forceinline__ float rowsum16(float v) {
    #pragma unroll
    for (int o = 8; o > 0; o >>= 1) v += __shfl_xor(v, o, 16);
    return v;
}

// ---------- K3: fused T/G tiles + online masked softmax + weighted cost ----------
__global__ __launch_bounds__(256) void fused_kernel(
    const float* __restrict__ src, const float* __restrict__ pred,
    const float* __restrict__ predW,
    const float* __restrict__ src_mask, const float* __restrict__ pred_mask,
    const float* __restrict__ src_sq, const float* __restrict__ pred_sq,
    float* __restrict__ m_part, float* __restrict__ l_part, float* __restrict__ w_part) {
    __shared__ float sP[PT][DK + 4];
    __shared__ float sPW[PT][DK + 4];
    __shared__ float sS[ST][DK + 4];
    int tid = threadIdx.x;
    int tx = tid & 15, ty = tid >> 4;
    int b = blockIdx.z;
    int split = blockIdx.y;
    int p0 = blockIdx.x * PT;
    int sBeg = split * (L_ / SPLIT);
    int sEnd = sBeg + (L_ / SPLIT);

    float pm[4], psq[4], mst[4], lst[4], wst[4];
    #pragma unroll
    for (int i = 0; i < 4; i++) {
        int p = p0 + ty * 4 + i;
        pm[i] = pred_mask[b * L_ + p];
        psq[i] = pred_sq[b * L_ + p];
        mst[i] = -1e30f; lst[i] = 0.f; wst[i] = 0.f;
    }

    const float* srcB = src + (size_t)b * L_ * D_;
    const float* predB = pred + (size_t)b * L_ * D_;
    const float* predWB = predW + (size_t)b * L_ * D_;

    #pragma unroll 1
    for (int s0 = sBeg; s0 < sEnd; s0 += ST) {
        float T[4][4] = {};
        float G[4][4] = {};
        #pragma unroll 1
        for (int d0 = 0; d0 < D_; d0 += DK) {
            #pragma unroll
            for (int rep = 0; rep < 2; rep++) {
                int idx = rep * 256 + tid;
                int r = idx >> 3;
                int c4 = (idx & 7) * 4;
                *(float4*)&sP[r][c4]  = *(const float4*)(predB  + (size_t)(p0 + r) * D_ + d0 + c4);
                *(float4*)&sPW[r][c4] = *(const float4*)(predWB + (size_t)(p0 + r) * D_ + d0 + c4);
                *(float4*)&sS[r][c4]  = *(const float4*)(srcB   + (size_t)(s0 + r) * D_ + d0 + c4);
            }
            __syncthreads();
            #pragma unroll
            for (int dd = 0; dd < DK; dd += 4) {
                float4 aP[4], aW[4], bS[4];
                #pragma unroll
                for (int i = 0; i < 4; i++) aP[i] = *(const float4*)&sP[ty * 4 + i][dd];
                #pragma unroll
                for (int i = 0; i < 4; i++) aW[i] = *(const float4*)&sPW[ty * 4 + i][dd];
                #pragma unroll
                for (int j = 0; j < 4; j++) bS[j] = *(const float4*)&sS[tx * 4 + j][dd];
                const float* ap = (const float*)aP;
                const float* aw = (const float*)aW;
                const float* bs = (const float*)bS;
                #pragma unroll
                for (int u = 0; u < 4; u++) {
                    #pragma unroll
                    for (int i = 0; i < 4; i++) {
                        float av = ap[i * 4 + u];
                        float wv = aw[i * 4 + u];
                        #pragma unroll
                        for (int j = 0; j < 4; j++) {
                            float sv = bs[j * 4 + u];
                            G[i][j] = fmaf(av, sv, G[i][j]);
                            T[i][j] = fmaf(wv, sv, T[i][j]);
                        }
                    }
                }
            }
            __syncthreads();
        }
        // online masked softmax + weighted-cost update
        float sm[4], ssq[4];
        #pragma unroll
        for (int j = 0; j < 4; j++) {
            int s = s0 + tx * 4 + j;
            sm[j] = src_mask[b * L_ + s];
            ssq[j] = src_sq[b * L_ + s];
        }
        #pragma unroll
        for (int i = 0; i < 4; i++) {
            float Tm[4];
            float tmax = -1e30f;
            #pragma unroll
            for (int j = 0; j < 4; j++) {
                bool msk = (pm[i] == 0.f) || (sm[j] == 0.f);
                Tm[j] = msk ? NEG_INF_V : T[i][j];
                tmax = fmaxf(tmax, Tm[j]);
            }
            tmax = rowmax16(tmax);
            float mnew = fmaxf(mst[i], tmax);
            float alpha = __expf(mst[i] - mnew);
            float pl = 0.f, pw = 0.f;
            #pragma unroll
            for (int j = 0; j < 4; j++) {
                float e = __expf(Tm[j] - mnew);
                float cc = psq[i] + ssq[j] - 2.f * G[i][j];
                float c = sqrtf(fmaxf(cc, 0.f));
                pl += e;
                pw = fmaf(e, c, pw);
            }
            pl = rowsum16(pl);
            pw = rowsum16(pw);
            lst[i] = lst[i] * alpha + pl;
            wst[i] = wst[i] * alpha + pw;
            mst[i] = mnew;
        }
    }
    if (tx == 0) {
        #pragma unroll
        for (int i = 0; i < 4; i++) {
            int p = p0 + ty * 4 + i;
            size_t o = ((size_t)(b * L_ + p)) * SPLIT + split;
            m_part[o] = mst[i];
            l_part[o] = lst[i];
            w_part[o] = wst[i];
        }
    }
}

// ---------- K4: combine splits, per-batch sums ----------
__global__ __launch_bounds__(256) void combine_kernel(
    const float* __restrict__ m_part, const float* __restrict__ l_part,
    const float* __restrict__ w_part,
    const float* __restrict__ x_mask, const float* __restrict__ y_mask,
    float* __restrict__ Sout) {
    int b = blockIdx.x;
    int tid = threadIdx.x;
    float s = 0.f, n1 = 0.f, n2 = 0.f;
    for (int p = tid; p < L_; p += 256) {
        size_t o = ((size_t)(b * L_ + p)) * SPLIT;
        float m0 = m_part[o], m1 = m_part[o + 1];
        float mm = fmaxf(m0, m1);
        float e0 = __expf(m0 - mm), e1 = __expf(m1 - mm);
        float l = l_part[o] * e0 + l_part[o + 1] * e1;
        float w = w_part[o] * e0 + w_part[o + 1] * e1;
        s += w / l;
        n1 += y_mask[b * L_ + p];
        n2 += x_mask[b * L_ + p];
    }
    __shared__ float red[3][256];
    red[0][tid] = s; red[1][tid] = n1; red[2][tid] = n2;
    __syncthreads();
    for (int o = 128; o > 0; o >>= 1) {
        if (tid < o) {
            red[0][tid] += red[0][tid + o];
            red[1][tid] += red[1][tid + o];
            red[2][tid] += red[2][tid + o];
        }
        __syncthreads();
    }
    if (tid == 0) {
        Sout[b] = red[0][0];
        Sout[B_ + b] = red[1][0];
        Sout[2 * B_ + b] = red[2][0];
    }
}

// ---------- K5: final scalar ----------
__global__ void final_kernel(const float* __restrict__ Sarr, float* __restrict__ out) {
    if (threadIdx.x == 0 && blockIdx.x == 0) {
        float ss = 0.f, si = 0.f;
        for (int b = 0; b < B_; b++) {
            ss += Sarr[b];
            si += 1.0f / (Sarr[B_ + b] * Sarr[2 * B_ + b]);
        }
        out[0] = ss * si / (float)(B_ * B_);  // LAMBDA_W = 1.0
    }
}

extern "C" void kernel_launch(void* const* d_in, const int* in_sizes, int n_in,
                              void* d_out, int out_size, void* d_ws, size_t ws_size,
                              hipStream_t stream) {
    const float* h_x = (const float*)d_in[0];     // src
    const float* h_y = (const float*)d_in[1];     // pred
    const float* x_mask = (const float*)d_in[2];  // src_mask
    const float* y_mask = (const float*)d_in[3];  // pred_mask
    const float* W = (const float*)d_in[4];

    float* ws = (float*)d_ws;
    float* predW = ws;                                // B*L*D
    float* pred_sq = predW + (size_t)B_ * L_ * D_;    // B*L
    float* src_sq = pred_sq + B_ * L_;                // B*L
    float* m_part = src_sq + B_ * L_;                 // B*L*SPLIT
    float* l_part = m_part + (size_t)B_ * L_ * SPLIT;
    float* w_part = l_part + (size_t)B_ * L_ * SPLIT;
    float* Sarr = w_part + (size_t)B_ * L_ * SPLIT;   // 3*B

    rowsq_kernel<<<B_ * L_ / 4, 256, 0, stream>>>(h_y, pred_sq);
    rowsq_kernel<<<B_ * L_ / 4, 256, 0, stream>>>(h_x, src_sq);
    predw_kernel<<<dim3(B_ * L_ / 64, D_ / 64), 256, 0, stream>>>(h_y, W, predW);
    fused_kernel<<<dim3(L_ / PT, SPLIT, B_), 256, 0, stream>>>(
        h_x, h_y, predW, x_mask, y_mask, src_sq, pred_sq, m_part, l_part, w_part);
    combine_kernel<<<B_, 256, 0, stream>>>(m_part, l_part, w_part, x_mask, y_mask, Sarr);
    final_kernel<<<1, 64, 0, stream>>>(Sarr, (float*)d_out);
}

// Round 2
// 204.138 us; speedup vs baseline: 4.2800x; 4.2800x over previous
//
#include <hip/hip_runtime.h>
#include <math.h>
#include <stdint.h>

#define B_ 8
#define L_ 2048
#define D_ 256
#define NEG_INF_V (-1e10f)
#define NSTRIP 32

typedef __bf16 bf16x8 __attribute__((ext_vector_type(8)));
typedef float f32x4 __attribute__((ext_vector_type(4)));

__device__ __forceinline__ void load_lds16(const void* g, void* l) {
    __builtin_amdgcn_global_load_lds(
        (const __attribute__((address_space(1))) void*)g,
        (__attribute__((address_space(3))) void*)l, 16, 0, 0);
}

// ---------- K0: fp32 -> bf16 conversions (+ W transpose) ----------
__global__ __launch_bounds__(256) void convert_kernel(
    const float* __restrict__ x, const float* __restrict__ y,
    const float* __restrict__ W,
    __bf16* __restrict__ xb, __bf16* __restrict__ yb, __bf16* __restrict__ Wt) {
    int tid = threadIdx.x;
    size_t blk = blockIdx.x;
    if (blk < 8192) {
        const float* srcp = (blk < 4096) ? x : y;
    __bf16* dstp = (blk < 4096) ? xb : yb;
        size_t i = (((blk & 4095) * 256) + tid) * 4;
        float4 v = *(const float4*)(srcp + i);
        union { __bf16 o[4]; uint64_t u; } cv;
        cv.o[0] = (__bf16)v.x; cv.o[1] = (__bf16)v.y;
        cv.o[2] = (__bf16)v.z; cv.o[3] = (__bf16)v.w;
        *(uint64_t*)(dstp + i) = cv.u;
    } else {
        // W transpose: Wt[n][k] = W[k][n]; 64 blocks
        int kq = (int)(blk - 8192);      // 0..63
        int n = tid;                     // 0..255
        int k0 = kq * 4;
        union { __bf16 o[4]; uint64_t u; } cv;
        #pragma unroll
        for (int j = 0; j < 4; j++) cv.o[j] = (__bf16)W[(size_t)(k0 + j) * D_ + n];
        *(uint64_t*)(Wt + (size_t)n * D_ + k0) = cv.u;
    }
}

// ---------- K1: per-row sum of squares (fp32, exact) ----------
__global__ __launch_bounds__(256) void rowsq_kernel(const float* __restrict__ x,
                                                    float* __restrict__ out) {
    int row = blockIdx.x * 4 + (threadIdx.x >> 6);
    int lane = threadIdx.x & 63;
    const float4* p = (const float4*)(x + (size_t)row * D_);
    float4 v = p[lane];
    float s = v.x * v.x + v.y * v.y + v.z * v.z + v.w * v.w;
    #pragma unroll
    for (int o = 32; o > 0; o >>= 1) s += __shfl_xor(s, o, 64);
    if (lane == 0) out[row] = s;
}

// ---------- K2: predW = pred(bf16) x W -> bf16, MFMA ----------
__global__ __launch_bounds__(256, 2) void predw_mfma(
    const __bf16* __restrict__ pred, const __bf16* __restrict__ Wt,
    __bf16* __restrict__ out) {
    __shared__ __align__(16) __bf16 sA[128 * 32];
    __shared__ __align__(16) __bf16 sB[128 * 32];
    int tid = threadIdx.x, lane = tid & 63, wid = tid >> 6;
    int wp = wid >> 1, ws = wid & 1;
    int m0 = blockIdx.x * 128, n0 = blockIdx.y * 128;
    f32x4 acc[4][4] = {};
    char* la = (char*)sA;
    char* lb = (char*)sB;
    int ldRow = lane >> 2;
    int kcg = ((lane & 3) ^ ((lane >> 3) & 3)) * 8;
    for (int k0 = 0; k0 < D_; k0 += 32) {
        #pragma unroll
        for (int t = wid * 4; t < wid * 4 + 4; ++t) {
            int mat = t >> 3, seg = t & 7;
            int rl = seg * 16 + ldRow;
            const __bf16* g = (mat == 0 ? pred + ((size_t)(m0 + rl)) * D_
                                        : Wt + ((size_t)(n0 + rl)) * D_) + k0 + kcg;
            load_lds16(g, (mat == 0 ? la : lb) + seg * 1024);
        }
        __syncthreads();
        int m = lane & 15, q = lane >> 4;
        int pos = (q ^ ((m >> 1) & 3)) << 4;
        bf16x8 fA[4], fB[4];
        #pragma unroll
        for (int pt = 0; pt < 4; ++pt)
            fA[pt] = *(const bf16x8*)(la + (wp * 64 + pt * 16 + m) * 64 + pos);
        #pragma unroll
        for (int st = 0; st < 4; ++st)
            fB[st] = *(const bf16x8*)(lb + (ws * 64 + st * 16 + m) * 64 + pos);
        #pragma unroll
        for (int pt = 0; pt < 4; ++pt)
            #pragma unroll
            for (int st = 0; st < 4; ++st)
                acc[pt][st] = __builtin_amdgcn_mfma_f32_16x16x32_bf16(
                    fA[pt], fB[st], acc[pt][st], 0, 0, 0);
        __syncthreads();
    }
    int q = lane >> 4, cn = lane & 15;
    #pragma unroll
    for (int pt = 0; pt < 4; ++pt)
        #pragma unroll
        for (int st = 0; st < 4; ++st)
            #pragma unroll
            for (int r = 0; r < 4; ++r) {
                int row = m0 + wp * 64 + pt * 16 + q * 4 + r;
                int col = n0 + ws * 64 + st * 16 + cn;
                out[(size_t)row * D_ + col] = (__bf16)acc[pt][st][r];
            }
}

// ---------- K3: fused MFMA T/G + strip-local masked softmax + weighted cost ----------
__global__ __launch_bounds__(256, 2) void fused_mfma(
    const __bf16* __restrict__ srcb, const __bf16* __restrict__ predb,
    const __bf16* __restrict__ predWb,
    const float* __restrict__ src_mask, const float* __restrict__ pred_mask,
    const float* __restrict__ src_sq, const float* __restrict__ pred_sq,
    float* __restrict__ m_part, float* __restrict__ l_part,
    float* __restrict__ w_part) {
    __shared__ __align__(16) __bf16 sP[128 * 32];
    __shared__ __align__(16) __bf16 sW[128 * 32];
    __shared__ __align__(16) __bf16 sS[128 * 32];
    __shared__ float sPM[128], sPSQ[128], sSM[128], sSSQ[128];

    int tid = threadIdx.x, lane = tid & 63, wid = tid >> 6;
    int wp = wid >> 1, ws = wid & 1;
    int b = blockIdx.z;
    int p0 = blockIdx.x * 128;
    int s0 = blockIdx.y * 128;

    if (tid < 128) {
        sPM[tid] = pred_mask[b * L_ + p0 + tid];
        sPSQ[tid] = pred_sq[b * L_ + p0 + tid];
    } else {
        int t2 = tid & 127;
        sSM[t2] = src_mask[b * L_ + s0 + t2];
        sSSQ[t2] = src_sq[b * L_ + s0 + t2];
    }

    const __bf16* gP = predb + ((size_t)b * L_ + p0) * D_;
    const __bf16* gW = predWb + ((size_t)b * L_ + p0) * D_;
    const __bf16* gS = srcb + ((size_t)b * L_ + s0) * D_;

    f32x4 accT[4][4] = {};
    f32x4 accG[4][4] = {};
    char* lp = (char*)sP;
    char* lw = (char*)sW;
    char* ls = (char*)sS;
    int ldRow = lane >> 2;
    int kcg = ((lane & 3) ^ ((lane >> 3) & 3)) * 8;

    for (int k0 = 0; k0 < D_; k0 += 32) {
        #pragma unroll
        for (int t = wid * 6; t < wid * 6 + 6; ++t) {
            int mat = t >> 3, seg = t & 7;
            int rl = seg * 16 + ldRow;
            const __bf16* g = (mat == 0 ? gP : (mat == 1 ? gW : gS)) +
                              (size_t)rl * D_ + k0 + kcg;
            char* l = (mat == 0 ? lp : (mat == 1 ? lw : ls)) + seg * 1024;
            load_lds16(g, l);
        }
        __syncthreads();
        int m = lane & 15, q = lane >> 4;
        int pos = (q ^ ((m >> 1) & 3)) << 4;
        bf16x8 fP[4], fW[4], fS[4];
        #pragma unroll
        for (int pt = 0; pt < 4; ++pt) {
            int off = (wp * 64 + pt * 16 + m) * 64 + pos;
            fP[pt] = *(const bf16x8*)(lp + off);
            fW[pt] = *(const bf16x8*)(lw + off);
        }
        #pragma unroll
        for (int st = 0; st < 4; ++st)
            fS[st] = *(const bf16x8*)(ls + (ws * 64 + st * 16 + m) * 64 + pos);
        #pragma unroll
        for (int pt = 0; pt < 4; ++pt)
            #pragma unroll
            for (int st = 0; st < 4; ++st) {
                accT[pt][st] = __builtin_amdgcn_mfma_f32_16x16x32_bf16(
                    fW[pt], fS[st], accT[pt][st], 0, 0, 0);
                accG[pt][st] = __builtin_amdgcn_mfma_f32_16x16x32_bf16(
                    fP[pt], fS[st], accG[pt][st], 0, 0, 0);
            }
        __syncthreads();
    }

    // epilogue: per-row strip-local masked online-softmax partials
    int q = lane >> 4, cn = lane & 15;
    int strip = blockIdx.y * 2 + ws;
    float smv[4], ssqv[4];
    #pragma unroll
    for (int j = 0; j < 4; ++j) {
        int cl = ws * 64 + j * 16 + cn;
        smv[j] = sSM[cl];
        ssqv[j] = sSSQ[cl];
    }
    #pragma unroll
    for (int pt = 0; pt < 4; ++pt) {
        #pragma unroll
        for (int r = 0; r < 4; ++r) {
            int prl = wp * 64 + pt * 16 + q * 4 + r;
            float pm = sPM[prl], psq = sPSQ[prl];
            float Tv[4];
            float tm = -1e30f;
            #pragma unroll
            for (int j = 0; j < 4; ++j) {
                float tv = ((pm == 0.f) || (smv[j] == 0.f)) ? NEG_INF_V
                                                            : accT[pt][j][r];
                Tv[j] = tv;
                tm = fmaxf(tm, tv);
            }
            #pragma unroll
            for (int o = 8; o > 0; o >>= 1) tm = fmaxf(tm, __shfl_xor(tm, o, 64));
            float l = 0.f, w = 0.f;
            #pragma unroll
            for (int j = 0; j < 4; ++j) {
                float e = __expf(Tv[j] - tm);
                float cc = psq + ssqv[j] - 2.f * accG[pt][j][r];
                float c = sqrtf(fmaxf(cc, 0.f));
                l += e;
                w = fmaf(e, c, w);
            }
            #pragma unroll
            for (int o = 8; o > 0; o >>= 1) {
                l += __shfl_xor(l, o, 64);
                w += __shfl_xor(w, o, 64);
            }
            if (cn == 0) {
                size_t o = ((size_t)(b * L_ + p0 + prl)) * NSTRIP + strip;
                m_part[o] = tm;
                l_part[o] = l;
                w_part[o] = w;
            }
        }
    }
}

// ---------- K4: combine strips, per-batch sums ----------
__global__ __launch_bounds__(256) void combine_kernel(
    const float* __restrict__ m_part, const float* __restrict__ l_part,
    const float* __restrict__ w_part,
    const float* __restrict__ x_mask, const float* __restrict__ y_mask,
    float* __restrict__ Sout) {
    int b = blockIdx.x;
    int tid = threadIdx.x;
    float s = 0.f, n1 = 0.f, n2 = 0.f;
    for (int p = tid; p < L_; p += 256) {
        size_t base = ((size_t)(b * L_ + p)) * NSTRIP;
        float mm = -1e30f;
        for (int st = 0; st < NSTRIP; ++st) mm = fmaxf(mm, m_part[base + st]);
        float l = 0.f, w = 0.f;
        for (int st = 0; st < NSTRIP; ++st) {
            float e = __expf(m_part[base + st] - mm);
            l = fmaf(l_part[base + st], e, l);
            w = fmaf(w_part[base + st], e, w);
        }
        s += w / l;
        n1 += y_mask[b * L_ + p];
        n2 += x_mask[b * L_ + p];
    }
    __shared__ float red[3][256];
    red[0][tid] = s; red[1][tid] = n1; red[2][tid] = n2;
    __syncthreads();
    for (int o = 128; o > 0; o >>= 1) {
        if (tid < o) {
            red[0][tid] += red[0][tid + o];
            red[1][tid] += red[1][tid + o];
            red[2][tid] += red[2][tid + o];
        }
        __syncthreads();
    }
    if (tid == 0) {
        Sout[b] = red[0][0];
        Sout[B_ + b] = red[1][0];
        Sout[2 * B_ + b] = red[2][0];
    }
}

// ---------- K5: final scalar ----------
__global__ void final_kernel(const float* __restrict__ Sarr, float* __restrict__ out) {
    if (threadIdx.x == 0 && blockIdx.x == 0) {
        float ss = 0.f, si = 0.f;
        for (int b = 0; b < B_; b++) {
            ss += Sarr[b];
            si += 1.0f / (Sarr[B_ + b] * Sarr[2 * B_ + b]);
        }
        out[0] = ss * si / (float)(B_ * B_);  // LAMBDA_W = 1.0
    }
}

extern "C" void kernel_launch(void* const* d_in, const int* in_sizes, int n_in,
                              void* d_out, int out_size, void* d_ws, size_t ws_size,
                              hipStream_t stream) {
    const float* h_x = (const float*)d_in[0];     // src
    const float* h_y = (const float*)d_in[1];     // pred
    const float* x_mask = (const float*)d_in[2];  // src_mask
    const float* y_mask = (const float*)d_in[3];  // pred_mask
    const float* W = (const float*)d_in[4];

    char* w8 = (char*)d_ws;
    const size_t BLD2 = (size_t)B_ * L_ * D_ * 2;  // 8 MB
    __bf16* src_bf = (__bf16*)w8;
    __bf16* pred_bf = (__bf16*)(w8 + BLD2);
    __bf16* predW_bf = (__bf16*)(w8 + 2 * BLD2);
    __bf16* Wt = (__bf16*)(w8 + 3 * BLD2);                       // 128 KB
    float* pred_sq = (float*)(w8 + 3 * BLD2 + (1 << 17));        // 64 KB
    float* src_sq = (float*)(w8 + 3 * BLD2 + (1 << 17) + (1 << 16));
    char* pbase = w8 + 3 * BLD2 + (1 << 17) + (1 << 17);
    const size_t PSZ = (size_t)B_ * L_ * NSTRIP * 4;             // 2 MB each
    float* m_part = (float*)pbase;
    float* l_part = (float*)(pbase + PSZ);
    float* w_part = (float*)(pbase + 2 * PSZ);
    float* Sarr = (float*)(pbase + 3 * PSZ);

    convert_kernel<<<8256, 256, 0, stream>>>(h_x, h_y, W, src_bf, pred_bf, Wt);
    rowsq_kernel<<<B_ * L_ / 4, 256, 0, stream>>>(h_y, pred_sq);
    rowsq_kernel<<<B_ * L_ / 4, 256, 0, stream>>>(h_x, src_sq);
    predw_mfma<<<dim3(B_ * L_ / 128, 2), 256, 0, stream>>>(pred_bf, Wt, predW_bf);
    fused_mfma<<<dim3(L_ / 128, L_ / 128, B_), 256, 0, stream>>>(
        src_bf, pred_bf, predW_bf, x_mask, y_mask, src_sq, pred_sq,
        m_part, l_part, w_part);
    combine_kernel<<<B_, 256, 0, stream>>>(m_part, l_part, w_part, x_mask, y_mask, Sarr);
    final_kernel<<<1, 64, 0, stream>>>(Sarr, (float*)d_out);
}

// Round 3
// 179.109 us; speedup vs baseline: 4.8781x; 1.1397x over previous
//
#include <hip/hip_runtime.h>
#include <math.h>
#include <stdint.h>

#define B_ 8
#define L_ 2048
#define D_ 256
#define NEG_INF_V (-1e10f)
#define NSTRIP 32

typedef __bf16 bf16x8 __attribute__((ext_vector_type(8)));
typedef float f32x4 __attribute__((ext_vector_type(4)));

#define MFMA16(a, b, c) __builtin_amdgcn_mfma_f32_16x16x32_bf16((a), (b), (c), 0, 0, 0)

// Fragment-major (FM) layout for a [rows x 256] bf16 matrix:
// granule index = ((G * 8 + kb) * 64 + q * 16 + m) ; granule = 16B = 8 bf16
// holds M[G*16 + m][kb*32 + q*8 .. +8).  G = absolute row/16.
// A wave (lane = q*16+m) loads frag (G_tile, kb) as one coalesced 1KB segment.

// ---------- K0: fp32 -> bf16 FM transform + row sum-of-squares + W FM ----------
__global__ __launch_bounds__(256) void convert_kernel(
    const float* __restrict__ x, const float* __restrict__ y,
    const float* __restrict__ W,
    __bf16* __restrict__ srcFM, __bf16* __restrict__ predFM,
    __bf16* __restrict__ WFM,
    float* __restrict__ src_sq, float* __restrict__ pred_sq) {
    int tid = threadIdx.x;
    int blk = blockIdx.x;
    if (blk < 2048) {
        const float* in = (blk < 1024) ? x : y;
        __bf16* out = (blk < 1024) ? srcFM : predFM;
        float* sqout = (blk < 1024) ? src_sq : pred_sq;
        int g = blk & 1023;  // absolute row-group
        __shared__ float srow[16];
        if (tid < 16) srow[tid] = 0.f;
        __syncthreads();
        int m = tid & 15, q = (tid >> 4) & 3, kbh = tid >> 6;
        size_t rowb = ((size_t)g * 16 + m) * D_;
        float ss = 0.f;
        #pragma unroll
        for (int h = 0; h < 2; ++h) {
            int kb = kbh + h * 4;
            const float* p = in + rowb + kb * 32 + q * 8;
            float4 v0 = *(const float4*)p;
            float4 v1 = *(const float4*)(p + 4);
            ss += v0.x * v0.x + v0.y * v0.y + v0.z * v0.z + v0.w * v0.w +
                  v1.x * v1.x + v1.y * v1.y + v1.z * v1.z + v1.w * v1.w;
            union { __bf16 o[8]; bf16x8 v; } cv;
            cv.o[0] = (__bf16)v0.x; cv.o[1] = (__bf16)v0.y;
            cv.o[2] = (__bf16)v0.z; cv.o[3] = (__bf16)v0.w;
            cv.o[4] = (__bf16)v1.x; cv.o[5] = (__bf16)v1.y;
            cv.o[6] = (__bf16)v1.z; cv.o[7] = (__bf16)v1.w;
            *(bf16x8*)(out + (((size_t)g * 8 + kb) * 64 + q * 16 + m) * 8) = cv.v;
        }
        atomicAdd(&srow[m], ss);
        __syncthreads();
        if (tid < 16) sqout[g * 16 + tid] = srow[tid];
    } else {
        // W -> FM of W^T rows (B operand for predw GEMM): 32 blocks
        int idx = (blk - 2048) * 256 + tid;
        int m = idx & 15, q = (idx >> 4) & 3, kb = (idx >> 6) & 7, gn = idx >> 9;
        union { __bf16 o[8]; bf16x8 v; } cv;
        #pragma unroll
        for (int j = 0; j < 8; ++j)
            cv.o[j] = (__bf16)W[(size_t)(kb * 32 + q * 8 + j) * D_ + gn * 16 + m];
        *(bf16x8*)(WFM + (size_t)idx * 8) = cv.v;
    }
}

// ---------- K1: predW = pred x W, FM in / FM out, no K-loop LDS ----------
__global__ __launch_bounds__(256, 2) void predw_mfma(
    const __bf16* __restrict__ predFM, const __bf16* __restrict__ WFM,
    const float* __restrict__ pred_mask, __bf16* __restrict__ pwFM) {
    __shared__ __align__(16) __bf16 sT[128 * 136];
    __shared__ int flag;
    int tid = threadIdx.x, lane = tid & 63, wid = tid >> 6;
    int wp = wid >> 1, wn = wid & 1;
    int m0 = blockIdx.x * 128;  // absolute pred row
    int n0 = blockIdx.y * 128;  // output col (D dim)
    if (tid == 0) flag = 0;
    __syncthreads();
    if (tid < 128) { if (pred_mask[m0 + tid] != 0.f) atomicOr(&flag, 1); }
    __syncthreads();
    if (!flag) return;  // rows never used by T-GEMM

    const __bf16* bA = predFM + (size_t)(m0 / 16 + wp * 4) * 4096 + lane * 8;
    const __bf16* bB = WFM + (size_t)(n0 / 16 + wn * 4) * 4096 + lane * 8;
    f32x4 acc[4][4] = {};
    #pragma unroll
    for (int kb = 0; kb < 8; ++kb) {
        bf16x8 fA[4], fB[4];
        #pragma unroll
        for (int t = 0; t < 4; ++t) {
            fA[t] = *(const bf16x8*)(bA + (t * 8 + kb) * 512);
            fB[t] = *(const bf16x8*)(bB + (t * 8 + kb) * 512);
        }
        #pragma unroll
        for (int pt = 0; pt < 4; ++pt)
            #pragma unroll
            for (int st = 0; st < 4; ++st)
                acc[pt][st] = MFMA16(fA[pt], fB[st], acc[pt][st]);
    }
    int q = lane >> 4, cn = lane & 15;
    #pragma unroll
    for (int pt = 0; pt < 4; ++pt)
        #pragma unroll
        for (int st = 0; st < 4; ++st)
            #pragma unroll
            for (int r = 0; r < 4; ++r)
                sT[(wp * 64 + pt * 16 + q * 4 + r) * 136 + wn * 64 + st * 16 + cn] =
                    (__bf16)acc[pt][st][r];
    __syncthreads();
    #pragma unroll
    for (int i = 0; i < 8; ++i) {
        int idx = i * 256 + tid;
        int gl = idx >> 8, kbl = (idx >> 6) & 3, qq = (idx >> 4) & 3, mm = idx & 15;
        bf16x8 v = *(const bf16x8*)(sT + (gl * 16 + mm) * 136 + kbl * 32 + qq * 8);
        *(bf16x8*)(pwFM +
                   (((size_t)(m0 / 16 + gl) * 8 + n0 / 32 + kbl) * 64 + qq * 16 + mm) * 8) = v;
    }
}

// ---------- K2: fused barrier-free MFMA T/G + strip softmax partials ----------
__global__ __launch_bounds__(256, 2) void fused_mfma(
    const __bf16* __restrict__ srcFM, const __bf16* __restrict__ predFM,
    const __bf16* __restrict__ pwFM,
    const float* __restrict__ src_mask, const float* __restrict__ pred_mask,
    const float* __restrict__ src_sq, const float* __restrict__ pred_sq,
    float* __restrict__ m_part, float* __restrict__ l_part,
    float* __restrict__ w_part) {
    __shared__ float sPM[128], sPSQ[128], sSM[128], sSSQ[128];
    __shared__ int flg[3];  // 0: anyValidP, 1: anyValidS, 2: anyInvalidP
    int tid = threadIdx.x, lane = tid & 63, wid = tid >> 6;
    int wp = wid >> 1, ws = wid & 1;
    int b = blockIdx.z, p0 = blockIdx.x * 128, s0 = blockIdx.y * 128;
    if (tid < 3) flg[tid] = 0;
    __syncthreads();
    if (tid < 128) {
        float v = pred_mask[b * L_ + p0 + tid];
        sPM[tid] = v;
        sPSQ[tid] = pred_sq[b * L_ + p0 + tid];
        atomicOr(&flg[(v != 0.f) ? 0 : 2], 1);
    } else {
        int t = tid - 128;
        float v = src_mask[b * L_ + s0 + t];
        sSM[t] = v;
        sSSQ[t] = src_sq[b * L_ + s0 + t];
        if (v != 0.f) atomicOr(&flg[1], 1);
    }
    __syncthreads();
    const bool doT = flg[0] && flg[1];
    const bool doG = flg[2] || flg[1];
    int q = lane >> 4, cn = lane & 15;
    int strip = blockIdx.y * 2 + ws;
    if (!doT && !doG) {
        // all p valid & all s masked: strip weight is exactly 0 at combine
        if (cn == 0) {
            #pragma unroll
            for (int pt = 0; pt < 4; ++pt)
                #pragma unroll
                for (int r = 0; r < 4; ++r) {
                    int prow = wp * 64 + pt * 16 + q * 4 + r;
                    size_t o = ((size_t)(b * L_ + p0 + prow)) * NSTRIP + strip;
                    m_part[o] = NEG_INF_V; l_part[o] = 0.f; w_part[o] = 0.f;
                }
        }
        return;
    }

    const __bf16* bS = srcFM + ((size_t)b * 128 + blockIdx.y * 8 + ws * 4) * 4096 + lane * 8;
    const __bf16* bP = predFM + ((size_t)b * 128 + blockIdx.x * 8 + wp * 4) * 4096 + lane * 8;
    const __bf16* bW = pwFM + ((size_t)b * 128 + blockIdx.x * 8 + wp * 4) * 4096 + lane * 8;
    f32x4 accT[4][4] = {};
    f32x4 accG[4][4] = {};
    if (doT) {
        #pragma unroll
        for (int kb = 0; kb < 8; ++kb) {
            bf16x8 fS[4], fP[4], fW[4];
            #pragma unroll
            for (int st = 0; st < 4; ++st)
                fS[st] = *(const bf16x8*)(bS + (st * 8 + kb) * 512);
            #pragma unroll
            for (int pt = 0; pt < 4; ++pt) {
                fP[pt] = *(const bf16x8*)(bP + (pt * 8 + kb) * 512);
                fW[pt] = *(const bf16x8*)(bW + (pt * 8 + kb) * 512);
            }
            #pragma unroll
            for (int pt = 0; pt < 4; ++pt)
                #pragma unroll
                for (int st = 0; st < 4; ++st) {
                    accG[pt][st] = MFMA16(fP[pt], fS[st], accG[pt][st]);
                    accT[pt][st] = MFMA16(fW[pt], fS[st], accT[pt][st]);
                }
        }
    } else {
        #pragma unroll
        for (int kb = 0; kb < 8; ++kb) {
            bf16x8 fS[4], fP[4];
            #pragma unroll
            for (int st = 0; st < 4; ++st)
                fS[st] = *(const bf16x8*)(bS + (st * 8 + kb) * 512);
            #pragma unroll
            for (int pt = 0; pt < 4; ++pt)
                fP[pt] = *(const bf16x8*)(bP + (pt * 8 + kb) * 512);
            #pragma unroll
            for (int pt = 0; pt < 4; ++pt)
                #pragma unroll
                for (int st = 0; st < 4; ++st)
                    accG[pt][st] = MFMA16(fP[pt], fS[st], accG[pt][st]);
        }
    }

    // epilogue: per-row strip partials (m, l, w)
    float smv[4], ssqv[4];
    #pragma unroll
    for (int j = 0; j < 4; ++j) {
        int cl = ws * 64 + j * 16 + cn;
        smv[j] = sSM[cl];
        ssqv[j] = sSSQ[cl];
    }
    #pragma unroll
    for (int pt = 0; pt < 4; ++pt) {
        #pragma unroll
        for (int r = 0; r < 4; ++r) {
            int prow = wp * 64 + pt * 16 + q * 4 + r;
            float pm = sPM[prow], psq = sPSQ[prow];
            float Tv[4];
            float tm = -1e30f;
            #pragma unroll
            for (int j = 0; j < 4; ++j) {
                float tv = ((pm == 0.f) || (smv[j] == 0.f)) ? NEG_INF_V
                                                            : accT[pt][j][r];
                Tv[j] = tv;
                tm = fmaxf(tm, tv);
            }
            #pragma unroll
            for (int o = 8; o > 0; o >>= 1) tm = fmaxf(tm, __shfl_xor(tm, o, 16));
            float l = 0.f, w = 0.f;
            #pragma unroll
            for (int j = 0; j < 4; ++j) {
                float e = __expf(Tv[j] - tm);
                float cc = psq + ssqv[j] - 2.f * accG[pt][j][r];
                float c = sqrtf(fmaxf(cc, 0.f));
                l += e;
                w = fmaf(e, c, w);
            }
            #pragma unroll
            for (int o = 8; o > 0; o >>= 1) {
                l += __shfl_xor(l, o, 16);
                w += __shfl_xor(w, o, 16);
            }
            if (cn == 0) {
                size_t o = ((size_t)(b * L_ + p0 + prow)) * NSTRIP + strip;
                m_part[o] = tm;
                l_part[o] = l;
                w_part[o] = w;
            }
        }
    }
}

// ---------- K3: combine strips -> per-batch sums (atomic) ----------
__global__ __launch_bounds__(256) void combine_kernel(
    const float* __restrict__ m_part, const float* __restrict__ l_part,
    const float* __restrict__ w_part,
    const float* __restrict__ x_mask, const float* __restrict__ y_mask,
    float* __restrict__ Sarr) {
    int tid = threadIdx.x;
    int r = blockIdx.x * 256 + tid;  // 0..16383, one b per block
    int b = r >> 11;
    size_t base = (size_t)r * NSTRIP;
    float mm = -1e30f;
    for (int s = 0; s < NSTRIP; ++s) mm = fmaxf(mm, m_part[base + s]);
    float l = 0.f, w = 0.f;
    for (int s = 0; s < NSTRIP; ++s) {
        float e = __expf(m_part[base + s] - mm);
        l = fmaf(l_part[base + s], e, l);
        w = fmaf(w_part[base + s], e, w);
    }
    float sv = w / l;
    float n1 = y_mask[r], n2 = x_mask[r];
    __shared__ float red[3][256];
    red[0][tid] = sv; red[1][tid] = n1; red[2][tid] = n2;
    __syncthreads();
    for (int o = 128; o > 0; o >>= 1) {
        if (tid < o) {
            red[0][tid] += red[0][tid + o];
            red[1][tid] += red[1][tid + o];
            red[2][tid] += red[2][tid + o];
        }
        __syncthreads();
    }
    if (tid == 0) {
        atomicAdd(&Sarr[b], red[0][0]);
        atomicAdd(&Sarr[8 + b], red[1][0]);
        atomicAdd(&Sarr[16 + b], red[2][0]);
    }
}

// ---------- K4: final scalar ----------
__global__ void final_kernel(const float* __restrict__ Sarr, float* __restrict__ out) {
    if (threadIdx.x == 0 && blockIdx.x == 0) {
        float ss = 0.f, si = 0.f;
        for (int b = 0; b < B_; b++) {
            ss += Sarr[b];
            si += 1.0f / (Sarr[B_ + b] * Sarr[2 * B_ + b]);
        }
        out[0] = ss * si / (float)(B_ * B_);  // LAMBDA_W = 1.0
    }
}

extern "C" void kernel_launch(void* const* d_in, const int* in_sizes, int n_in,
                              void* d_out, int out_size, void* d_ws, size_t ws_size,
                              hipStream_t stream) {
    const float* h_x = (const float*)d_in[0];     // src
    const float* h_y = (const float*)d_in[1];     // pred
    const float* x_mask = (const float*)d_in[2];  // src_mask
    const float* y_mask = (const float*)d_in[3];  // pred_mask
    const float* W = (const float*)d_in[4];

    char* w8 = (char*)d_ws;
    const size_t BLD2 = (size_t)B_ * L_ * D_ * 2;  // 8 MB
    __bf16* srcFM = (__bf16*)w8;
    __bf16* predFM = (__bf16*)(w8 + BLD2);
    __bf16* pwFM = (__bf16*)(w8 + 2 * BLD2);
    __bf16* WFM = (__bf16*)(w8 + 3 * BLD2);                   // 128 KB
    float* src_sq = (float*)(w8 + 3 * BLD2 + (1 << 17));      // 64 KB
    float* pred_sq = (float*)(w8 + 3 * BLD2 + (1 << 17) + (1 << 16));
    char* pbase = w8 + 3 * BLD2 + (1 << 17) + (1 << 17);
    const size_t PSZ = (size_t)B_ * L_ * NSTRIP * 4;          // 2 MB each
    float* m_part = (float*)pbase;
    float* l_part = (float*)(pbase + PSZ);
    float* w_part = (float*)(pbase + 2 * PSZ);
    float* Sarr = (float*)(pbase + 3 * PSZ);                  // 24 floats

    convert_kernel<<<2080, 256, 0, stream>>>(h_x, h_y, W, srcFM, predFM, WFM,
                                             src_sq, pred_sq);
    predw_mfma<<<dim3(B_ * L_ / 128, D_ / 128), 256, 0, stream>>>(
        predFM, WFM, y_mask, pwFM);
    fused_mfma<<<dim3(L_ / 128, L_ / 128, B_), 256, 0, stream>>>(
        srcFM, predFM, pwFM, x_mask, y_mask, src_sq, pred_sq,
        m_part, l_part, w_part);
    hipMemsetAsync(Sarr, 0, 24 * sizeof(float), stream);
    combine_kernel<<<B_ * L_ / 256, 256, 0, stream>>>(m_part, l_part, w_part,
                                                      x_mask, y_mask, Sarr);
    final_kernel<<<1, 64, 0, stream>>>(Sarr, (float*)d_out);
}

// Round 4
// 172.878 us; speedup vs baseline: 5.0540x; 1.0360x over previous
//
#include <hip/hip_runtime.h>
#include <math.h>
#include <stdint.h>

#define B_ 8
#define L_ 2048
#define D_ 256
#define NEG_INF_V (-1e10f)
#define NSTRIP 32

typedef __bf16 bf16x8 __attribute__((ext_vector_type(8)));
typedef float f32x4 __attribute__((ext_vector_type(4)));

#define MFMA16(a, b, c) __builtin_amdgcn_mfma_f32_16x16x32_bf16((a), (b), (c), 0, 0, 0)

// Fragment-major (FM) layout for a [rows x 256] bf16 matrix:
// granule index = ((G * 8 + kb) * 64 + q * 16 + m) ; granule = 16B = 8 bf16
// holds M[G*16 + m][kb*32 + q*8 .. +8).  G = absolute row/16.
// A wave (lane = q*16+m) loads frag (G_tile, kb) as one coalesced 1KB segment.

// ---------- K0: fp32 -> bf16 FM transform + row sum-of-squares + W FM ----------
__global__ __launch_bounds__(256) void convert_kernel(
    const float* __restrict__ x, const float* __restrict__ y,
    const float* __restrict__ W,
    __bf16* __restrict__ srcFM, __bf16* __restrict__ predFM,
    __bf16* __restrict__ WFM,
    float* __restrict__ src_sq, float* __restrict__ pred_sq) {
    int tid = threadIdx.x;
    int blk = blockIdx.x;
    if (blk < 2048) {
        const float* in = (blk < 1024) ? x : y;
        __bf16* out = (blk < 1024) ? srcFM : predFM;
        float* sqout = (blk < 1024) ? src_sq : pred_sq;
        int g = blk & 1023;  // absolute row-group
        int lane = tid & 63, wid = tid >> 6;
        int m = tid & 15, q = (tid >> 4) & 3, kbh = wid;
        size_t rowb = ((size_t)g * 16 + m) * D_;
        float ss = 0.f;
        #pragma unroll
        for (int h = 0; h < 2; ++h) {
            int kb = kbh + h * 4;
            const float* p = in + rowb + kb * 32 + q * 8;
            float4 v0 = *(const float4*)p;
            float4 v1 = *(const float4*)(p + 4);
            ss += v0.x * v0.x + v0.y * v0.y + v0.z * v0.z + v0.w * v0.w +
                  v1.x * v1.x + v1.y * v1.y + v1.z * v1.z + v1.w * v1.w;
            union { __bf16 o[8]; bf16x8 v; } cv;
            cv.o[0] = (__bf16)v0.x; cv.o[1] = (__bf16)v0.y;
            cv.o[2] = (__bf16)v0.z; cv.o[3] = (__bf16)v0.w;
            cv.o[4] = (__bf16)v1.x; cv.o[5] = (__bf16)v1.y;
            cv.o[6] = (__bf16)v1.z; cv.o[7] = (__bf16)v1.w;
            *(bf16x8*)(out + (((size_t)g * 8 + kb) * 64 + q * 16 + m) * 8) = cv.v;
        }
        // reduce across q within wave, then across the 4 waves via LDS
        ss += __shfl_xor(ss, 16, 64);
        ss += __shfl_xor(ss, 32, 64);
        __shared__ float sred[4][16];
        if (lane < 16) sred[wid][lane] = ss;
        __syncthreads();
        if (tid < 16)
            sqout[g * 16 + tid] =
                sred[0][tid] + sred[1][tid] + sred[2][tid] + sred[3][tid];
    } else {
        // W -> FM of W^T rows (B operand for predw GEMM): 32 blocks
        int idx = (blk - 2048) * 256 + tid;
        int m = idx & 15, q = (idx >> 4) & 3, kb = (idx >> 6) & 7, gn = idx >> 9;
        union { __bf16 o[8]; bf16x8 v; } cv;
        #pragma unroll
        for (int j = 0; j < 8; ++j)
            cv.o[j] = (__bf16)W[(size_t)(kb * 32 + q * 8 + j) * D_ + gn * 16 + m];
        *(bf16x8*)(WFM + (size_t)idx * 8) = cv.v;
    }
}

// ---------- K1: predW = pred x W, FM in / FM out (XCD-swizzled) ----------
__global__ __launch_bounds__(256, 2) void predw_mfma(
    const __bf16* __restrict__ predFM, const __bf16* __restrict__ WFM,
    const float* __restrict__ pred_mask, __bf16* __restrict__ pwFM) {
    __shared__ __align__(16) __bf16 sT[128 * 136];
    __shared__ int flag;
    int tid = threadIdx.x, lane = tid & 63, wid = tid >> 6;
    int wp = wid >> 1, wn = wid & 1;
    int id = blockIdx.x;                 // 256 blocks: b + 8*xm + 128*ny
    int m0 = (((id >> 3) & 15) + (id & 7) * 16) * 128;  // absolute pred row
    int n0 = (id >> 7) * 128;            // output col block
    if (tid == 0) flag = 0;
    __syncthreads();
    if (tid < 128) { if (pred_mask[m0 + tid] != 0.f) atomicOr(&flag, 1); }
    __syncthreads();
    if (!flag) return;  // rows never used by T-GEMM

    const __bf16* bA = predFM + (size_t)(m0 / 16 + wp * 4) * 4096 + lane * 8;
    const __bf16* bB = WFM + (size_t)(n0 / 16 + wn * 4) * 4096 + lane * 8;
    f32x4 acc[4][4] = {};
    #pragma unroll
    for (int kb = 0; kb < 8; ++kb) {
        bf16x8 fA[4], fB[4];
        #pragma unroll
        for (int t = 0; t < 4; ++t) {
            fA[t] = *(const bf16x8*)(bA + (t * 8 + kb) * 512);
            fB[t] = *(const bf16x8*)(bB + (t * 8 + kb) * 512);
        }
        #pragma unroll
        for (int pt = 0; pt < 4; ++pt)
            #pragma unroll
            for (int st = 0; st < 4; ++st)
                acc[pt][st] = MFMA16(fA[pt], fB[st], acc[pt][st]);
    }
    int q = lane >> 4, cn = lane & 15;
    #pragma unroll
    for (int pt = 0; pt < 4; ++pt)
        #pragma unroll
        for (int st = 0; st < 4; ++st)
            #pragma unroll
            for (int r = 0; r < 4; ++r)
                sT[(wp * 64 + pt * 16 + q * 4 + r) * 136 + wn * 64 + st * 16 + cn] =
                    (__bf16)acc[pt][st][r];
    __syncthreads();
    #pragma unroll
    for (int i = 0; i < 8; ++i) {
        int idx = i * 256 + tid;
        int gl = idx >> 8, kbl = (idx >> 6) & 3, qq = (idx >> 4) & 3, mm = idx & 15;
        bf16x8 v = *(const bf16x8*)(sT + (gl * 16 + mm) * 136 + kbl * 32 + qq * 8);
        *(bf16x8*)(pwFM +
                   (((size_t)(m0 / 16 + gl) * 8 + n0 / 32 + kbl) * 64 + qq * 16 + mm) * 8) = v;
    }
}

// ---------- K2: fused T/G MFMA, role-split waves, 64p x 128s tile ----------
// waves 0-1: T = pwFM . srcFM^T ; waves 2-3: G = predFM . srcFM^T -> LDS
// XCD swizzle: blockIdx.x = b + 8*px + 256*sy  (b&7 locks batch to XCD)
__global__ __launch_bounds__(256, 3) void fused_mfma(
    const __bf16* __restrict__ srcFM, const __bf16* __restrict__ predFM,
    const __bf16* __restrict__ pwFM,
    const float* __restrict__ src_mask, const float* __restrict__ pred_mask,
    const float* __restrict__ src_sq, const float* __restrict__ pred_sq,
    float* __restrict__ m_part, float* __restrict__ l_part,
    float* __restrict__ w_part) {
    __shared__ float sG[2][64][68];  // [ws][prow][scol], pitch 68: 2-way banks
    __shared__ float sPM[64], sPSQ[64], sSM[128], sSSQ[128];
    __shared__ int flg[3];  // 0: anyValidP, 1: anyValidS, 2: anyInvalidP
    int tid = threadIdx.x, lane = tid & 63, wid = tid >> 6;
    int role = wid >> 1, ws = wid & 1;
    int id = blockIdx.x;
    int b = id & 7, px = (id >> 3) & 31, sy = id >> 8;
    int p0 = px * 64, s0 = sy * 128;
    int q = lane >> 4, cn = lane & 15;

    if (tid < 3) flg[tid] = 0;
    __syncthreads();
    if (tid < 64) {
        float v = pred_mask[b * L_ + p0 + tid];
        sPM[tid] = v;
        sPSQ[tid] = pred_sq[b * L_ + p0 + tid];
        atomicOr(&flg[(v != 0.f) ? 0 : 2], 1);
    } else if (tid < 192) {
        int t = tid - 64;
        float v = src_mask[b * L_ + s0 + t];
        sSM[t] = v;
        sSSQ[t] = src_sq[b * L_ + s0 + t];
        if (v != 0.f) atomicOr(&flg[1], 1);
    }
    __syncthreads();
    const bool doT = flg[0] && flg[1];
    const bool doG = flg[2] || flg[1];
    int strip = sy * 2 + ws;

    if (!doT && !doG) {
        // all p valid & all s masked: strip gets exactly 0 weight at combine
        if (role == 0 && cn == 0) {
            #pragma unroll
            for (int pt = 0; pt < 4; ++pt)
                #pragma unroll
                for (int r = 0; r < 4; ++r) {
                    int prow = pt * 16 + q * 4 + r;
                    size_t o = ((size_t)(b * L_ + p0 + prow)) * NSTRIP + strip;
                    m_part[o] = NEG_INF_V; l_part[o] = 0.f; w_part[o] = 0.f;
                }
        }
        return;
    }

    const __bf16* bB = srcFM + ((size_t)(b * 128 + sy * 8 + ws * 4)) * 4096 + lane * 8;
    const __bf16* bA = (role == 0 ? pwFM : predFM) +
                       ((size_t)(b * 128 + px * 4)) * 4096 + lane * 8;
    f32x4 acc[4][4] = {};
    if (role == 1 || doT) {
        #pragma unroll
        for (int kb = 0; kb < 8; ++kb) {
            bf16x8 fA[4], fB[4];
            #pragma unroll
            for (int t = 0; t < 4; ++t) {
                fA[t] = *(const bf16x8*)(bA + (t * 8 + kb) * 512);
                fB[t] = *(const bf16x8*)(bB + (t * 8 + kb) * 512);
            }
            #pragma unroll
            for (int pt = 0; pt < 4; ++pt)
                #pragma unroll
                for (int st = 0; st < 4; ++st)
                    acc[pt][st] = MFMA16(fA[pt], fB[st], acc[pt][st]);
        }
    }
    if (role == 1) {
        #pragma unroll
        for (int pt = 0; pt < 4; ++pt)
            #pragma unroll
            for (int st = 0; st < 4; ++st)
                #pragma unroll
                for (int r = 0; r < 4; ++r)
                    sG[ws][pt * 16 + q * 4 + r][st * 16 + cn] = acc[pt][st][r];
    }
    __syncthreads();
    if (role == 1) return;

    // T-wave epilogue: per-row strip partials (m, l, w); G from LDS
    float smv[4], ssqv[4];
    #pragma unroll
    for (int j = 0; j < 4; ++j) {
        int cl = ws * 64 + j * 16 + cn;
        smv[j] = sSM[cl];
        ssqv[j] = sSSQ[cl];
    }
    #pragma unroll
    for (int pt = 0; pt < 4; ++pt) {
        #pragma unroll
        for (int r = 0; r < 4; ++r) {
            int prow = pt * 16 + q * 4 + r;
            float pm = sPM[prow], psq = sPSQ[prow];
            float Tv[4], Gv[4];
            float tm = -1e30f;
            #pragma unroll
            for (int j = 0; j < 4; ++j) {
                Gv[j] = sG[ws][prow][j * 16 + cn];
                float tv = ((pm == 0.f) || (smv[j] == 0.f)) ? NEG_INF_V
                                                            : acc[pt][j][r];
                Tv[j] = tv;
                tm = fmaxf(tm, tv);
            }
            #pragma unroll
            for (int o = 8; o > 0; o >>= 1) tm = fmaxf(tm, __shfl_xor(tm, o, 16));
            float l = 0.f, w = 0.f;
            #pragma unroll
            for (int j = 0; j < 4; ++j) {
                float e = __expf(Tv[j] - tm);
                float cc = psq + ssqv[j] - 2.f * Gv[j];
                float c = sqrtf(fmaxf(cc, 0.f));
                l += e;
                w = fmaf(e, c, w);
            }
            #pragma unroll
            for (int o = 8; o > 0; o >>= 1) {
                l += __shfl_xor(l, o, 16);
                w += __shfl_xor(w, o, 16);
            }
            if (cn == 0) {
                size_t o = ((size_t)(b * L_ + p0 + prow)) * NSTRIP + strip;
                m_part[o] = tm;
                l_part[o] = l;
                w_part[o] = w;
            }
        }
    }
}

// ---------- K3: combine strips -> per-batch sums (atomic) ----------
__global__ __launch_bounds__(256) void combine_kernel(
    const float* __restrict__ m_part, const float* __restrict__ l_part,
    const float* __restrict__ w_part,
    const float* __restrict__ x_mask, const float* __restrict__ y_mask,
    float* __restrict__ Sarr) {
    int tid = threadIdx.x;
    int r = blockIdx.x * 256 + tid;  // 0..16383, one b per block
    int b = r >> 11;
    size_t base = (size_t)r * NSTRIP;
    float mm = -1e30f;
    for (int s = 0; s < NSTRIP; ++s) mm = fmaxf(mm, m_part[base + s]);
    float l = 0.f, w = 0.f;
    for (int s = 0; s < NSTRIP; ++s) {
        float e = __expf(m_part[base + s] - mm);
        l = fmaf(l_part[base + s], e, l);
        w = fmaf(w_part[base + s], e, w);
    }
    float sv = w / l;
    float n1 = y_mask[r], n2 = x_mask[r];
    __shared__ float red[3][256];
    red[0][tid] = sv; red[1][tid] = n1; red[2][tid] = n2;
    __syncthreads();
    for (int o = 128; o > 0; o >>= 1) {
        if (tid < o) {
            red[0][tid] += red[0][tid + o];
            red[1][tid] += red[1][tid + o];
            red[2][tid] += red[2][tid + o];
        }
        __syncthreads();
    }
    if (tid == 0) {
        atomicAdd(&Sarr[b], red[0][0]);
        atomicAdd(&Sarr[8 + b], red[1][0]);
        atomicAdd(&Sarr[16 + b], red[2][0]);
    }
}

// ---------- K4: final scalar ----------
__global__ void final_kernel(const float* __restrict__ Sarr, float* __restrict__ out) {
    if (threadIdx.x == 0 && blockIdx.x == 0) {
        float ss = 0.f, si = 0.f;
        for (int b = 0; b < B_; b++) {
            ss += Sarr[b];
            si += 1.0f / (Sarr[B_ + b] * Sarr[2 * B_ + b]);
        }
        out[0] = ss * si / (float)(B_ * B_);  // LAMBDA_W = 1.0
    }
}

extern "C" void kernel_launch(void* const* d_in, const int* in_sizes, int n_in,
                              void* d_out, int out_size, void* d_ws, size_t ws_size,
                              hipStream_t stream) {
    const float* h_x = (const float*)d_in[0];     // src
    const float* h_y = (const float*)d_in[1];     // pred
    const float* x_mask = (const float*)d_in[2];  // src_mask
    const float* y_mask = (const float*)d_in[3];  // pred_mask
    const float* W = (const float*)d_in[4];

    char* w8 = (char*)d_ws;
    const size_t BLD2 = (size_t)B_ * L_ * D_ * 2;  // 8 MB
    __bf16* srcFM = (__bf16*)w8;
    __bf16* predFM = (__bf16*)(w8 + BLD2);
    __bf16* pwFM = (__bf16*)(w8 + 2 * BLD2);
    __bf16* WFM = (__bf16*)(w8 + 3 * BLD2);                   // 128 KB
    float* src_sq = (float*)(w8 + 3 * BLD2 + (1 << 17));      // 64 KB
    float* pred_sq = (float*)(w8 + 3 * BLD2 + (1 << 17) + (1 << 16));
    char* pbase = w8 + 3 * BLD2 + (1 << 17) + (1 << 17);
    const size_t PSZ = (size_t)B_ * L_ * NSTRIP * 4;          // 2 MB each
    float* m_part = (float*)pbase;
    float* l_part = (float*)(pbase + PSZ);
    float* w_part = (float*)(pbase + 2 * PSZ);
    float* Sarr = (float*)(pbase + 3 * PSZ);                  // 24 floats

    convert_kernel<<<2080, 256, 0, stream>>>(h_x, h_y, W, srcFM, predFM, WFM,
                                             src_sq, pred_sq);
    predw_mfma<<<256, 256, 0, stream>>>(predFM, WFM, y_mask, pwFM);
    fused_mfma<<<4096, 256, 0, stream>>>(
        srcFM, predFM, pwFM, x_mask, y_mask, src_sq, pred_sq,
        m_part, l_part, w_part);
    hipMemsetAsync(Sarr, 0, 24 * sizeof(float), stream);
    combine_kernel<<<B_ * L_ / 256, 256, 0, stream>>>(m_part, l_part, w_part,
                                                      x_mask, y_mask, Sarr);
    final_kernel<<<1, 64, 0, stream>>>(Sarr, (float*)d_out);
}